// Round 1
// baseline (344.587 us; speedup 1.0000x reference)
//
#include <hip/hip_runtime.h>

#define B_   8
#define S_   4096
#define D_   1024
#define M_   (B_ * S_)   // 32768 rows
#define N_   (2 * D_)    // 2048 cols (hidden | gate)
#define K_   D_          // 1024
#define CCH  128         // scan chunks
#define LCH  32          // chunk length (CCH*LCH == S_)

typedef __attribute__((ext_vector_type(8))) short bf16x8;
typedef __attribute__((ext_vector_type(4))) float f32x4;

__device__ __forceinline__ unsigned short f2bf(float f) {
  union { float f; unsigned u; } v; v.f = f;
  unsigned u = v.u;
  u = u + 0x7fffu + ((u >> 16) & 1u);   // RNE
  return (unsigned short)(u >> 16);
}
__device__ __forceinline__ float bf2f(unsigned short h) {
  union { unsigned u; float f; } v; v.u = ((unsigned)h) << 16;
  return v.f;
}
__device__ __forceinline__ float sigmoidf_(float x) {
  return 1.0f / (1.0f + __expf(-x));
}

// ---------- fp32 -> bf16 convert (x4 vectorized, grid-stride) ----------
__global__ __launch_bounds__(256) void k_cvt(const float* __restrict__ in,
                                             unsigned short* __restrict__ out,
                                             int n4) {
  int i = blockIdx.x * 256 + threadIdx.x;
  const int stride = gridDim.x * 256;
  for (; i < n4; i += stride) {
    float4 v = reinterpret_cast<const float4*>(in)[i];
    ushort4 o;
    o.x = f2bf(v.x); o.y = f2bf(v.y); o.z = f2bf(v.z); o.w = f2bf(v.w);
    reinterpret_cast<ushort4*>(out)[i] = o;
  }
}

// ---------- bf16 GEMM (m97 structure: 128x128 tile, BK=64, global_load_lds w16)
// C[row, e] = sum_k x[row,k] * W[e,k];  e<1024 -> G plane = g(hidden),
// e>=1024 -> Z plane = sigmoid(gate).
__global__ __launch_bounds__(256) void k_gemm(const unsigned short* __restrict__ xb,
                                              const unsigned short* __restrict__ wb,
                                              unsigned short* __restrict__ Gp,
                                              unsigned short* __restrict__ Zp) {
  __shared__ unsigned short As[128 * 64];
  __shared__ unsigned short Bs[128 * 64];
  const int tid = threadIdx.x;
  int wg = blockIdx.x;
  wg = (wg & 7) * 512 + (wg >> 3);      // XCD swizzle; 4096 % 8 == 0 -> bijective
  const int bm = wg >> 4;               // 0..255 (M panels)
  const int bn = wg & 15;               // 0..15  (N panels)
  const int lane = tid & 63;
  const int wm = ((tid >> 6) >> 1) * 64;   // wave row offset in tile
  const int wn = ((tid >> 6) & 1) * 64;    // wave col offset in tile

  // staging: 128 rows x 64 cols bf16 = 16KB, 256 thr x 16B x 4 issues
  const int srow  = tid >> 3;           // 0..31
  const int scolb = (tid & 7) * 16;     // byte offset within 128B row
  const char* ag = (const char*)xb + (size_t)(bm * 128 + srow) * 2048 + scolb;
  const char* bg = (const char*)wb + (size_t)(bn * 128 + srow) * 2048 + scolb;
  unsigned short* al = As + srow * 64 + (tid & 7) * 8;
  unsigned short* bl = Bs + srow * 64 + (tid & 7) * 8;

  f32x4 acc[4][4] = {};

  for (int kt = 0; kt < (K_ / 64); ++kt) {
#pragma unroll
    for (int i = 0; i < 4; ++i) {
      __builtin_amdgcn_global_load_lds(
          (const __attribute__((address_space(1))) void*)(ag + (size_t)i * 32 * 2048),
          (__attribute__((address_space(3))) void*)(al + i * 32 * 64), 16, 0, 0);
      __builtin_amdgcn_global_load_lds(
          (const __attribute__((address_space(1))) void*)(bg + (size_t)i * 32 * 2048),
          (__attribute__((address_space(3))) void*)(bl + i * 32 * 64), 16, 0, 0);
    }
    ag += 128; bg += 128;               // advance 64 k-elements
    __syncthreads();
#pragma unroll
    for (int ks = 0; ks < 2; ++ks) {
      bf16x8 af[4], bfr[4];
#pragma unroll
      for (int m = 0; m < 4; ++m)
        af[m] = *(const bf16x8*)&As[(wm + m * 16 + (lane & 15)) * 64 + ks * 32 + (lane >> 4) * 8];
#pragma unroll
      for (int n = 0; n < 4; ++n)
        bfr[n] = *(const bf16x8*)&Bs[(wn + n * 16 + (lane & 15)) * 64 + ks * 32 + (lane >> 4) * 8];
#pragma unroll
      for (int m = 0; m < 4; ++m)
#pragma unroll
        for (int n = 0; n < 4; ++n)
          acc[m][n] = __builtin_amdgcn_mfma_f32_16x16x32_bf16(af[m], bfr[n], acc[m][n], 0, 0, 0);
    }
    __syncthreads();
  }

  // epilogue: C/D layout col = lane&15, row = (lane>>4)*4 + reg  [m89-verified]
  const int row0 = bm * 128 + wm + ((lane >> 4) << 2);
  const int col0 = bn * 128 + wn + (lane & 15);
  if (bn < 8) {  // hidden half -> g(hidden)
#pragma unroll
    for (int m = 0; m < 4; ++m)
#pragma unroll
      for (int n = 0; n < 4; ++n)
#pragma unroll
        for (int i = 0; i < 4; ++i) {
          float v = acc[m][n][i];
          float g = (v >= 0.0f) ? (v + 0.5f) : sigmoidf_(v);
          Gp[(size_t)(row0 + m * 16 + i) * 1024 + (col0 + n * 16)] = f2bf(g);
        }
  } else {       // gate half -> z = sigmoid(gate)
#pragma unroll
    for (int m = 0; m < 4; ++m)
#pragma unroll
      for (int n = 0; n < 4; ++n)
#pragma unroll
        for (int i = 0; i < 4; ++i) {
          float v = acc[m][n][i];
          Zp[(size_t)(row0 + m * 16 + i) * 1024 + (col0 + n * 16 - 1024)] = f2bf(sigmoidf_(v));
        }
  }
}

// ---------- scan phase 1: per-chunk local scan (h from 0) + a-product ----------
// channel = b*1024 + d; each thread owns 4 consecutive d. Layout Ap/Hp: [CCH][8192]
__global__ __launch_bounds__(256) void k_scan1(const unsigned short* __restrict__ Gp,
                                               const unsigned short* __restrict__ Zp,
                                               float* __restrict__ Ap,
                                               float* __restrict__ Hp) {
  const int gid = blockIdx.x * 256 + threadIdx.x;   // 0..2047
  const int c = blockIdx.y;
  const int b = gid >> 8;
  const int d0 = (gid & 255) << 2;
  size_t base = ((size_t)b * S_ + (size_t)c * LCH) * 1024 + d0;
  float4 aP = {1.f, 1.f, 1.f, 1.f};
  float4 h  = {0.f, 0.f, 0.f, 0.f};
#pragma unroll 8
  for (int s = 0; s < LCH; ++s) {
    ushort4 zu = *reinterpret_cast<const ushort4*>(Zp + base);
    ushort4 gu = *reinterpret_cast<const ushort4*>(Gp + base);
    float z0 = bf2f(zu.x), z1 = bf2f(zu.y), z2 = bf2f(zu.z), z3 = bf2f(zu.w);
    float a0 = 1.f - z0,   a1 = 1.f - z1,   a2 = 1.f - z2,   a3 = 1.f - z3;
    h.x = fmaf(a0, h.x, z0 * bf2f(gu.x));
    h.y = fmaf(a1, h.y, z1 * bf2f(gu.y));
    h.z = fmaf(a2, h.z, z2 * bf2f(gu.z));
    h.w = fmaf(a3, h.w, z3 * bf2f(gu.w));
    aP.x *= a0; aP.y *= a1; aP.z *= a2; aP.w *= a3;
    base += 1024;
  }
  reinterpret_cast<float4*>(Ap)[(size_t)c * 2048 + gid] = aP;
  reinterpret_cast<float4*>(Hp)[(size_t)c * 2048 + gid] = h;
}

// ---------- scan phase 2: sequential carry over chunks ----------
__global__ __launch_bounds__(256) void k_scan2(const float* __restrict__ Ap,
                                               const float* __restrict__ Hp,
                                               float* __restrict__ Cin) {
  const int gid = blockIdx.x * 256 + threadIdx.x;   // 0..2047
  float4 carry = {0.f, 0.f, 0.f, 0.f};
  for (int c = 0; c < CCH; ++c) {
    reinterpret_cast<float4*>(Cin)[(size_t)c * 2048 + gid] = carry;
    float4 a = reinterpret_cast<const float4*>(Ap)[(size_t)c * 2048 + gid];
    float4 hh = reinterpret_cast<const float4*>(Hp)[(size_t)c * 2048 + gid];
    carry.x = fmaf(a.x, carry.x, hh.x);
    carry.y = fmaf(a.y, carry.y, hh.y);
    carry.z = fmaf(a.z, carry.z, hh.z);
    carry.w = fmaf(a.w, carry.w, hh.w);
  }
}

// ---------- scan phase 3: replay with carry, write fp32 out ----------
__global__ __launch_bounds__(256) void k_scan3(const unsigned short* __restrict__ Gp,
                                               const unsigned short* __restrict__ Zp,
                                               const float* __restrict__ Cin,
                                               float* __restrict__ out) {
  const int gid = blockIdx.x * 256 + threadIdx.x;
  const int c = blockIdx.y;
  const int b = gid >> 8;
  const int d0 = (gid & 255) << 2;
  size_t base = ((size_t)b * S_ + (size_t)c * LCH) * 1024 + d0;
  float4 h = reinterpret_cast<const float4*>(Cin)[(size_t)c * 2048 + gid];
#pragma unroll 8
  for (int s = 0; s < LCH; ++s) {
    ushort4 zu = *reinterpret_cast<const ushort4*>(Zp + base);
    ushort4 gu = *reinterpret_cast<const ushort4*>(Gp + base);
    float z0 = bf2f(zu.x), z1 = bf2f(zu.y), z2 = bf2f(zu.z), z3 = bf2f(zu.w);
    h.x = fmaf(1.f - z0, h.x, z0 * bf2f(gu.x));
    h.y = fmaf(1.f - z1, h.y, z1 * bf2f(gu.y));
    h.z = fmaf(1.f - z2, h.z, z2 * bf2f(gu.z));
    h.w = fmaf(1.f - z3, h.w, z3 * bf2f(gu.w));
    *reinterpret_cast<float4*>(out + base) = h;
    base += 1024;
  }
}

extern "C" void kernel_launch(void* const* d_in, const int* in_sizes, int n_in,
                              void* d_out, int out_size, void* d_ws, size_t ws_size,
                              hipStream_t stream) {
  const float* x = (const float*)d_in[0];   // [8,4096,1024] f32
  const float* W = (const float*)d_in[1];   // [2048,1024]  f32
  float* out = (float*)d_out;               // [8,4096,1024] f32

  unsigned char* w = (unsigned char*)d_ws;
  // layout: xb(64MB+) | wb(4MB) | Gp(64MB) | Zp(64MB). Ap/Hp/Cin alias xb
  // (xb is dead after k_gemm; 3 x 4MB << 64MB).
  unsigned short* xb = (unsigned short*)(w);
  unsigned short* wb = (unsigned short*)(w + 67108864);
  unsigned short* Gp = (unsigned short*)(w + 67108864 + 4194304);
  unsigned short* Zp = (unsigned short*)(w + 67108864 + 4194304 + 67108864);
  float* Ap  = (float*)(w);
  float* Hp  = (float*)(w + 4194304);
  float* Cin = (float*)(w + 8388608);

  k_cvt<<<4096, 256, 0, stream>>>(x, xb, (M_ * K_) / 4);
  k_cvt<<<2048, 256, 0, stream>>>(W, wb, (N_ * K_) / 4);
  k_gemm<<<(M_ / 128) * (N_ / 128), 256, 0, stream>>>(xb, wb, Gp, Zp);
  k_scan1<<<dim3(8, CCH), 256, 0, stream>>>(Gp, Zp, Ap, Hp);
  k_scan2<<<8, 256, 0, stream>>>(Ap, Hp, Cin);
  k_scan3<<<dim3(8, CCH), 256, 0, stream>>>(Gp, Zp, Cin, out);
}

// Round 2
// 276.986 us; speedup vs baseline: 1.2441x; 1.2441x over previous
//
#include <hip/hip_runtime.h>

#define B_   8
#define S_   4096
#define D_   1024
#define M_   (B_ * S_)   // 32768 rows
#define N_   (2 * D_)    // 2048 cols (hidden | gate)
#define K_   D_          // 1024
#define CCH  128         // scan chunks
#define LCH  32          // chunk length (CCH*LCH == S_)

#define BK   32
#define NT   (K_ / BK)   // 32 k-tiles

typedef __attribute__((ext_vector_type(8))) short bf16x8;
typedef __attribute__((ext_vector_type(4))) float f32x4;

__device__ __forceinline__ unsigned short f2bf(float f) {
  union { float f; unsigned u; } v; v.f = f;
  unsigned u = v.u;
  u = u + 0x7fffu + ((u >> 16) & 1u);   // RNE
  return (unsigned short)(u >> 16);
}
__device__ __forceinline__ float bf2f(unsigned short h) {
  union { unsigned u; float f; } v; v.u = ((unsigned)h) << 16;
  return v.f;
}
__device__ __forceinline__ float sigmoidf_(float x) {
  return 1.0f / (1.0f + __expf(-x));
}

#define GLL(src, dst) __builtin_amdgcn_global_load_lds(                     \
      (const __attribute__((address_space(1))) void*)(src),                 \
      (__attribute__((address_space(3))) void*)(dst), 16, 0, 0)

// ---------- fp32 -> bf16 convert (x4 vectorized, grid-stride) ----------
__global__ __launch_bounds__(256) void k_cvt(const float* __restrict__ in,
                                             unsigned short* __restrict__ out,
                                             int n4) {
  int i = blockIdx.x * 256 + threadIdx.x;
  const int stride = gridDim.x * 256;
  for (; i < n4; i += stride) {
    float4 v = reinterpret_cast<const float4*>(in)[i];
    ushort4 o;
    o.x = f2bf(v.x); o.y = f2bf(v.y); o.z = f2bf(v.z); o.w = f2bf(v.w);
    reinterpret_cast<ushort4*>(out)[i] = o;
  }
}

// ---------- bf16 GEMM: 256x256 tile, BK=32, 3-deep LDS ring, counted vmcnt ----
// C[row, e] = sum_k x[row,k] * W[e,k];  e<1024 -> G plane = g(hidden),
// e>=1024 -> Z plane = sigmoid(gate).
__global__ __launch_bounds__(512, 2) void k_gemm(const unsigned short* __restrict__ xb,
                                                 const unsigned short* __restrict__ wb,
                                                 unsigned short* __restrict__ Gp,
                                                 unsigned short* __restrict__ Zp) {
  // ring: 3 slots x (A 256x32 | B 256x32) bf16 = 3 x 32KB = 96KB
  __shared__ unsigned short lds[3 * 16384];
  const int tid = threadIdx.x;
  int wg = blockIdx.x;
  wg = (wg & 7) * 128 + (wg >> 3);     // XCD swizzle; 1024 % 8 == 0 -> bijective
  const int bm = wg >> 3;              // 0..127
  const int bn = wg & 7;               // 0..7
  const int lane = tid & 63;
  const int wid = tid >> 6;
  const int wr = wid >> 2;             // 0..1  (wave row: 128-row band)
  const int wc = wid & 3;              // 0..3  (wave col: 64-col band)

  // staging: per k-tile, A = 256x32x2B = 16KB = 512thr x 16B x 2 issues; B same
  const int srow = tid >> 2;           // 0..127
  const int scol = (tid & 3) * 16;     // byte within 64B row
  const char* agB = (const char*)xb + (size_t)(bm * 256 + srow) * 2048 + scol;
  const char* bgB = (const char*)wb + (size_t)(bn * 256 + srow) * 2048 + scol;
  unsigned short* const dst0 = &lds[srow * 32 + (tid & 3) * 8];

  f32x4 acc[8][4] = {};

  // prologue: stage tiles 0,1 into slots 0,1 (8 loads in flight)
  {
    const char* pa = agB;  const char* pb = bgB;
    GLL(pa, dst0);                 GLL(pa + 128 * 2048, dst0 + 4096);
    GLL(pb, dst0 + 8192);          GLL(pb + 128 * 2048, dst0 + 12288);
    pa += 64; pb += 64;
    GLL(pa, dst0 + 16384);         GLL(pa + 128 * 2048, dst0 + 20480);
    GLL(pb, dst0 + 24576);         GLL(pb + 128 * 2048, dst0 + 28672);
  }
  const char* aNext = agB + 2 * 64;    // tile 2 source
  const char* bNext = bgB + 2 * 64;

  const int fr = lane & 15;
  const int fq = (lane >> 4) * 8;
  int sl = 0;                          // slot of tile t
  int sn = 2;                          // slot of tile t+2

  for (int t = 0; t < NT - 1; ++t) {
    // tile t landed (tile t+1's 4 loads may stay outstanding); then barrier
    asm volatile("s_waitcnt vmcnt(4)\n\ts_barrier" ::: "memory");
    if (t < NT - 2) {                  // stage tile t+2 into freed slot
      unsigned short* d = dst0 + sn * 16384;
      GLL(aNext, d);                 GLL(aNext + 128 * 2048, d + 4096);
      GLL(bNext, d + 8192);          GLL(bNext + 128 * 2048, d + 12288);
      aNext += 64; bNext += 64;
    }
    const unsigned short* As = &lds[sl * 16384];
    const unsigned short* Bs = As + 8192;
    bf16x8 av[8], bv[4];
#pragma unroll
    for (int m = 0; m < 8; ++m)
      av[m] = *(const bf16x8*)&As[(wr * 128 + m * 16 + fr) * 32 + fq];
#pragma unroll
    for (int n = 0; n < 4; ++n)
      bv[n] = *(const bf16x8*)&Bs[(wc * 64 + n * 16 + fr) * 32 + fq];
    __builtin_amdgcn_s_setprio(1);
#pragma unroll
    for (int m = 0; m < 8; ++m)
#pragma unroll
      for (int n = 0; n < 4; ++n)
        acc[m][n] = __builtin_amdgcn_mfma_f32_16x16x32_bf16(av[m], bv[n], acc[m][n], 0, 0, 0);
    __builtin_amdgcn_s_setprio(0);
    sl = (sl == 2) ? 0 : sl + 1;
    sn = (sn == 2) ? 0 : sn + 1;
  }
  // peeled last tile: full drain
  {
    asm volatile("s_waitcnt vmcnt(0)\n\ts_barrier" ::: "memory");
    const unsigned short* As = &lds[sl * 16384];
    const unsigned short* Bs = As + 8192;
    bf16x8 av[8], bv[4];
#pragma unroll
    for (int m = 0; m < 8; ++m)
      av[m] = *(const bf16x8*)&As[(wr * 128 + m * 16 + fr) * 32 + fq];
#pragma unroll
    for (int n = 0; n < 4; ++n)
      bv[n] = *(const bf16x8*)&Bs[(wc * 64 + n * 16 + fr) * 32 + fq];
    __builtin_amdgcn_s_setprio(1);
#pragma unroll
    for (int m = 0; m < 8; ++m)
#pragma unroll
      for (int n = 0; n < 4; ++n)
        acc[m][n] = __builtin_amdgcn_mfma_f32_16x16x32_bf16(av[m], bv[n], acc[m][n], 0, 0, 0);
    __builtin_amdgcn_s_setprio(0);
  }

  // epilogue: C/D layout col = lane&15, row = (lane>>4)*4 + reg  [m89-verified]
  const int row0 = bm * 256 + wr * 128 + ((lane >> 4) << 2);
  const int col0 = bn * 256 + wc * 64 + fr;
  if (bn < 4) {  // hidden half -> g(hidden)
#pragma unroll
    for (int m = 0; m < 8; ++m)
#pragma unroll
      for (int n = 0; n < 4; ++n)
#pragma unroll
        for (int i = 0; i < 4; ++i) {
          float v = acc[m][n][i];
          float g = (v >= 0.0f) ? (v + 0.5f) : sigmoidf_(v);
          Gp[(size_t)(row0 + m * 16 + i) * 1024 + (col0 + n * 16)] = f2bf(g);
        }
  } else {       // gate half -> z = sigmoid(gate)
#pragma unroll
    for (int m = 0; m < 8; ++m)
#pragma unroll
      for (int n = 0; n < 4; ++n)
#pragma unroll
        for (int i = 0; i < 4; ++i) {
          float v = acc[m][n][i];
          Zp[(size_t)(row0 + m * 16 + i) * 1024 + (col0 + n * 16 - 1024)] = f2bf(sigmoidf_(v));
        }
  }
}

// ---------- scan phase 1: per-chunk local scan (h from 0) + a-product ----------
__global__ __launch_bounds__(256) void k_scan1(const unsigned short* __restrict__ Gp,
                                               const unsigned short* __restrict__ Zp,
                                               float* __restrict__ Ap,
                                               float* __restrict__ Hp) {
  const int gid = blockIdx.x * 256 + threadIdx.x;   // 0..2047
  const int c = blockIdx.y;
  const int b = gid >> 8;
  const int d0 = (gid & 255) << 2;
  size_t base = ((size_t)b * S_ + (size_t)c * LCH) * 1024 + d0;
  float4 aP = {1.f, 1.f, 1.f, 1.f};
  float4 h  = {0.f, 0.f, 0.f, 0.f};
#pragma unroll 8
  for (int s = 0; s < LCH; ++s) {
    ushort4 zu = *reinterpret_cast<const ushort4*>(Zp + base);
    ushort4 gu = *reinterpret_cast<const ushort4*>(Gp + base);
    float z0 = bf2f(zu.x), z1 = bf2f(zu.y), z2 = bf2f(zu.z), z3 = bf2f(zu.w);
    float a0 = 1.f - z0,   a1 = 1.f - z1,   a2 = 1.f - z2,   a3 = 1.f - z3;
    h.x = fmaf(a0, h.x, z0 * bf2f(gu.x));
    h.y = fmaf(a1, h.y, z1 * bf2f(gu.y));
    h.z = fmaf(a2, h.z, z2 * bf2f(gu.z));
    h.w = fmaf(a3, h.w, z3 * bf2f(gu.w));
    aP.x *= a0; aP.y *= a1; aP.z *= a2; aP.w *= a3;
    base += 1024;
  }
  reinterpret_cast<float4*>(Ap)[(size_t)c * 2048 + gid] = aP;
  reinterpret_cast<float4*>(Hp)[(size_t)c * 2048 + gid] = h;
}

// ---------- scan phase 2: sequential carry over chunks ----------
__global__ __launch_bounds__(256) void k_scan2(const float* __restrict__ Ap,
                                               const float* __restrict__ Hp,
                                               float* __restrict__ Cin) {
  const int gid = blockIdx.x * 256 + threadIdx.x;   // 0..2047
  float4 carry = {0.f, 0.f, 0.f, 0.f};
  for (int c = 0; c < CCH; ++c) {
    reinterpret_cast<float4*>(Cin)[(size_t)c * 2048 + gid] = carry;
    float4 a = reinterpret_cast<const float4*>(Ap)[(size_t)c * 2048 + gid];
    float4 hh = reinterpret_cast<const float4*>(Hp)[(size_t)c * 2048 + gid];
    carry.x = fmaf(a.x, carry.x, hh.x);
    carry.y = fmaf(a.y, carry.y, hh.y);
    carry.z = fmaf(a.z, carry.z, hh.z);
    carry.w = fmaf(a.w, carry.w, hh.w);
  }
}

// ---------- scan phase 3: replay with carry, write fp32 out ----------
__global__ __launch_bounds__(256) void k_scan3(const unsigned short* __restrict__ Gp,
                                               const unsigned short* __restrict__ Zp,
                                               const float* __restrict__ Cin,
                                               float* __restrict__ out) {
  const int gid = blockIdx.x * 256 + threadIdx.x;
  const int c = blockIdx.y;
  const int b = gid >> 8;
  const int d0 = (gid & 255) << 2;
  size_t base = ((size_t)b * S_ + (size_t)c * LCH) * 1024 + d0;
  float4 h = reinterpret_cast<const float4*>(Cin)[(size_t)c * 2048 + gid];
#pragma unroll 8
  for (int s = 0; s < LCH; ++s) {
    ushort4 zu = *reinterpret_cast<const ushort4*>(Zp + base);
    ushort4 gu = *reinterpret_cast<const ushort4*>(Gp + base);
    float z0 = bf2f(zu.x), z1 = bf2f(zu.y), z2 = bf2f(zu.z), z3 = bf2f(zu.w);
    h.x = fmaf(1.f - z0, h.x, z0 * bf2f(gu.x));
    h.y = fmaf(1.f - z1, h.y, z1 * bf2f(gu.y));
    h.z = fmaf(1.f - z2, h.z, z2 * bf2f(gu.z));
    h.w = fmaf(1.f - z3, h.w, z3 * bf2f(gu.w));
    *reinterpret_cast<float4*>(out + base) = h;
    base += 1024;
  }
}

extern "C" void kernel_launch(void* const* d_in, const int* in_sizes, int n_in,
                              void* d_out, int out_size, void* d_ws, size_t ws_size,
                              hipStream_t stream) {
  const float* x = (const float*)d_in[0];   // [8,4096,1024] f32
  const float* W = (const float*)d_in[1];   // [2048,1024]  f32
  float* out = (float*)d_out;               // [8,4096,1024] f32

  unsigned char* w = (unsigned char*)d_ws;
  // layout: xb(64MB) | wb(4MB) | Gp(64MB) | Zp(64MB). Ap/Hp/Cin alias xb
  // (xb is dead after k_gemm; 3 x 4MB << 64MB).
  unsigned short* xb = (unsigned short*)(w);
  unsigned short* wb = (unsigned short*)(w + 67108864);
  unsigned short* Gp = (unsigned short*)(w + 67108864 + 4194304);
  unsigned short* Zp = (unsigned short*)(w + 67108864 + 4194304 + 67108864);
  float* Ap  = (float*)(w);
  float* Hp  = (float*)(w + 4194304);
  float* Cin = (float*)(w + 8388608);

  k_cvt<<<4096, 256, 0, stream>>>(x, xb, (M_ * K_) / 4);
  k_cvt<<<2048, 256, 0, stream>>>(W, wb, (N_ * K_) / 4);
  k_gemm<<<(M_ / 256) * (N_ / 256), 512, 0, stream>>>(xb, wb, Gp, Zp);
  k_scan1<<<dim3(8, CCH), 256, 0, stream>>>(Gp, Zp, Ap, Hp);
  k_scan2<<<8, 256, 0, stream>>>(Ap, Hp, Cin);
  k_scan3<<<dim3(8, CCH), 256, 0, stream>>>(Gp, Zp, Cin, out);
}

// Round 3
// 265.249 us; speedup vs baseline: 1.2991x; 1.0442x over previous
//
#include <hip/hip_runtime.h>

#define B_   8
#define S_   4096
#define D_   1024
#define M_   (B_ * S_)   // 32768 rows
#define N_   (2 * D_)    // 2048 cols (hidden | gate)
#define K_   D_          // 1024
#define CCH  128         // scan chunks
#define LCH  32          // chunk length (CCH*LCH == S_)

#define BK   64
#define NT   (K_ / BK)   // 16 k-tiles

typedef __attribute__((ext_vector_type(8))) short bf16x8;
typedef __attribute__((ext_vector_type(4))) float f32x4;

__device__ __forceinline__ unsigned short f2bf(float f) {
  union { float f; unsigned u; } v; v.f = f;
  unsigned u = v.u;
  u = u + 0x7fffu + ((u >> 16) & 1u);   // RNE
  return (unsigned short)(u >> 16);
}
__device__ __forceinline__ float bf2f(unsigned short h) {
  union { unsigned u; float f; } v; v.u = ((unsigned)h) << 16;
  return v.f;
}
__device__ __forceinline__ float sigmoidf_(float x) {
  return 1.0f / (1.0f + __expf(-x));
}

#define GLL(src, dst) __builtin_amdgcn_global_load_lds(                     \
      (const __attribute__((address_space(1))) void*)(src),                 \
      (__attribute__((address_space(3))) void*)(dst), 16, 0, 0)

// ---------- fp32 -> bf16 convert (x4 vectorized, grid-stride) ----------
__global__ __launch_bounds__(256) void k_cvt(const float* __restrict__ in,
                                             unsigned short* __restrict__ out,
                                             int n4) {
  int i = blockIdx.x * 256 + threadIdx.x;
  const int stride = gridDim.x * 256;
  for (; i < n4; i += stride) {
    float4 v = reinterpret_cast<const float4*>(in)[i];
    ushort4 o;
    o.x = f2bf(v.x); o.y = f2bf(v.y); o.z = f2bf(v.z); o.w = f2bf(v.w);
    reinterpret_cast<ushort4*>(out)[i] = o;
  }
}

// ---------- bf16 GEMM: 256x256, BK=64, 8-phase-style interleave, dbuf LDS ----
// XOR-swizzled LDS (blk ^= row&7, both-sides with linear global_load_lds dest
// via pre-swizzled per-lane SOURCE). Counted vmcnt(8) per K-tile, 2 barriers
// per K-tile, GLL pairs interleaved between 16-MFMA setprio clusters.
__global__ __launch_bounds__(512, 2) void k_gemm(const unsigned short* __restrict__ xb,
                                                 const unsigned short* __restrict__ wb,
                                                 unsigned short* __restrict__ Gp,
                                                 unsigned short* __restrict__ Zp) {
  // [buf0: A 32KB | B 32KB][buf1: A 32KB | B 32KB] = 128 KiB
  __shared__ unsigned short lds[65536];
  const int tid = threadIdx.x;
  int wg = blockIdx.x;
  wg = (wg & 7) * 128 + (wg >> 3);     // XCD swizzle; 1024 % 8 == 0 -> bijective
  const int bm = wg >> 3;              // 0..127
  const int bn = wg & 7;               // 0..7
  const int lane = tid & 63;
  const int wid = tid >> 6;
  const int wr = wid >> 2;             // 0..1  (128-row band)
  const int wc = wid & 3;              // 0..3  (64-col band)
  const int fr = lane & 15;
  const int hi = lane >> 4;            // 0..3
  const int f7 = fr & 7;

  // ---- staging geometry: 8 chunks/tile (A c0..3, B c0..3), each 64 rows x 128B
  // thread -> (srow = tid>>3 in 0..63, sblk = tid&7). LDS dest linear: tid*16.
  // source column pre-swizzled so LDS[row][blk] holds global block blk^(row&7).
  const int srow = tid >> 3;
  const int sblk = tid & 7;
  const int scol = ((sblk ^ (srow & 7)) * 16);
  const char* aS = (const char*)xb + (size_t)(bm * 256 + srow) * 2048 + scol;
  const char* bS = (const char*)wb + (size_t)(bn * 256 + srow) * 2048 + scol;
  char* const ldsc = (char*)lds + (size_t)tid * 16;

  // stage all 8 chunks of K-tile tt into buffer bufb (byte offset)
#define STAGE_PAIR(srcbase, kbyte, bufbyte, region, C0)                      \
  GLL((srcbase) + (size_t)(C0) * 131072 + (kbyte),                           \
      ldsc + (bufbyte) + (region) + (C0) * 8192);                            \
  GLL((srcbase) + (size_t)((C0) + 1) * 131072 + (kbyte),                     \
      ldsc + (bufbyte) + (region) + ((C0) + 1) * 8192)

  f32x4 acc[8][4] = {};
  bf16x8 av[8], bv[4];

  // prologue: tile0 -> buf0, tile1 -> buf1 (16 loads in flight)
  STAGE_PAIR(aS, 0, 0, 0, 0);       STAGE_PAIR(aS, 0, 0, 0, 2);
  STAGE_PAIR(bS, 0, 0, 32768, 0);   STAGE_PAIR(bS, 0, 0, 32768, 2);
  STAGE_PAIR(aS, 128, 65536, 0, 0);     STAGE_PAIR(aS, 128, 65536, 0, 2);
  STAGE_PAIR(bS, 128, 65536, 32768, 0); STAGE_PAIR(bS, 128, 65536, 32768, 2);

  const int swz0 = (hi ^ f7) * 8;          // kk=0 element offset
  const int swz1 = ((4 + hi) ^ f7) * 8;    // kk=1

#define LOAD_FRAGS(Ab, Bb, SWZ)                                              \
  _Pragma("unroll") for (int m = 0; m < 8; ++m)                              \
    av[m] = *(const bf16x8*)&(Ab)[(wr * 128 + m * 16 + fr) * 64 + (SWZ)];    \
  _Pragma("unroll") for (int n = 0; n < 4; ++n)                              \
    bv[n] = *(const bf16x8*)&(Bb)[(wc * 64 + n * 16 + fr) * 64 + (SWZ)];

#define PHASE(M0)                                                            \
  __builtin_amdgcn_s_setprio(1);                                             \
  _Pragma("unroll") for (int m = (M0); m < (M0) + 2; ++m)                    \
    _Pragma("unroll") for (int n = 0; n < 4; ++n)                            \
      acc[m][n] = __builtin_amdgcn_mfma_f32_16x16x32_bf16(av[m], bv[n],      \
                                                          acc[m][n], 0, 0, 0); \
  __builtin_amdgcn_s_setprio(0);

#define PHASE4(M0)                                                           \
  __builtin_amdgcn_s_setprio(1);                                             \
  _Pragma("unroll") for (int m = (M0); m < (M0) + 4; ++m)                    \
    _Pragma("unroll") for (int n = 0; n < 4; ++n)                            \
      acc[m][n] = __builtin_amdgcn_mfma_f32_16x16x32_bf16(av[m], bv[n],      \
                                                          acc[m][n], 0, 0, 0); \
  __builtin_amdgcn_s_setprio(0);

  for (int t = 0; t < NT; ++t) {
    // tile t landed (my own 8 oldest loads done); barrier => landed for all
    if (t < NT - 1) asm volatile("s_waitcnt vmcnt(8)\n\ts_barrier" ::: "memory");
    else            asm volatile("s_waitcnt vmcnt(0)\n\ts_barrier" ::: "memory");

    const unsigned short* Ab = &lds[(t & 1) << 15];
    const unsigned short* Bb = Ab + 16384;
    const int bufbyte = (t & 1) * 65536;
    const size_t kbyte = (size_t)(t + 2) * 128;

    // ---- kk = 0: reads + 2 MFMA phases (overlaps other waves' LDS reads)
    LOAD_FRAGS(Ab, Bb, swz0);
    PHASE4(0);
    PHASE4(4);
    // ---- kk = 1 reads, then buffer is fully read -> barrier, then stage t+2
    LOAD_FRAGS(Ab, Bb, swz1);
    asm volatile("s_waitcnt lgkmcnt(0)\n\ts_barrier" ::: "memory");

    if (t < NT - 2) { STAGE_PAIR(aS, kbyte, bufbyte, 0, 0); }
    PHASE(0);
    if (t < NT - 2) { STAGE_PAIR(aS, kbyte, bufbyte, 0, 2); }
    PHASE(2);
    if (t < NT - 2) { STAGE_PAIR(bS, kbyte, bufbyte, 32768, 0); }
    PHASE(4);
    if (t < NT - 2) { STAGE_PAIR(bS, kbyte, bufbyte, 32768, 2); }
    PHASE(6);
  }

  // epilogue: C/D layout col = lane&15, row = (lane>>4)*4 + reg  [m89-verified]
  const int row0 = bm * 256 + wr * 128 + (hi << 2);
  const int col0 = bn * 256 + wc * 64 + fr;
  if (bn < 4) {  // hidden half -> g(hidden)
#pragma unroll
    for (int m = 0; m < 8; ++m)
#pragma unroll
      for (int n = 0; n < 4; ++n)
#pragma unroll
        for (int i = 0; i < 4; ++i) {
          float v = acc[m][n][i];
          float g = (v >= 0.0f) ? (v + 0.5f) : sigmoidf_(v);
          Gp[(size_t)(row0 + m * 16 + i) * 1024 + (col0 + n * 16)] = f2bf(g);
        }
  } else {       // gate half -> z = sigmoid(gate)
#pragma unroll
    for (int m = 0; m < 8; ++m)
#pragma unroll
      for (int n = 0; n < 4; ++n)
#pragma unroll
        for (int i = 0; i < 4; ++i) {
          float v = acc[m][n][i];
          Zp[(size_t)(row0 + m * 16 + i) * 1024 + (col0 + n * 16 - 1024)] = f2bf(sigmoidf_(v));
        }
  }
}

// ---------- scan phase 1: per-chunk local scan (h from 0) + a-product ----------
__global__ __launch_bounds__(256) void k_scan1(const unsigned short* __restrict__ Gp,
                                               const unsigned short* __restrict__ Zp,
                                               float* __restrict__ Ap,
                                               float* __restrict__ Hp) {
  const int gid = blockIdx.x * 256 + threadIdx.x;   // 0..2047
  const int c = blockIdx.y;
  const int b = gid >> 8;
  const int d0 = (gid & 255) << 2;
  size_t base = ((size_t)b * S_ + (size_t)c * LCH) * 1024 + d0;
  float4 aP = {1.f, 1.f, 1.f, 1.f};
  float4 h  = {0.f, 0.f, 0.f, 0.f};
#pragma unroll 8
  for (int s = 0; s < LCH; ++s) {
    ushort4 zu = *reinterpret_cast<const ushort4*>(Zp + base);
    ushort4 gu = *reinterpret_cast<const ushort4*>(Gp + base);
    float z0 = bf2f(zu.x), z1 = bf2f(zu.y), z2 = bf2f(zu.z), z3 = bf2f(zu.w);
    float a0 = 1.f - z0,   a1 = 1.f - z1,   a2 = 1.f - z2,   a3 = 1.f - z3;
    h.x = fmaf(a0, h.x, z0 * bf2f(gu.x));
    h.y = fmaf(a1, h.y, z1 * bf2f(gu.y));
    h.z = fmaf(a2, h.z, z2 * bf2f(gu.z));
    h.w = fmaf(a3, h.w, z3 * bf2f(gu.w));
    aP.x *= a0; aP.y *= a1; aP.z *= a2; aP.w *= a3;
    base += 1024;
  }
  reinterpret_cast<float4*>(Ap)[(size_t)c * 2048 + gid] = aP;
  reinterpret_cast<float4*>(Hp)[(size_t)c * 2048 + gid] = h;
}

// ---------- scan phase 2: sequential carry over chunks ----------
__global__ __launch_bounds__(256) void k_scan2(const float* __restrict__ Ap,
                                               const float* __restrict__ Hp,
                                               float* __restrict__ Cin) {
  const int gid = blockIdx.x * 256 + threadIdx.x;   // 0..2047
  float4 carry = {0.f, 0.f, 0.f, 0.f};
  for (int c = 0; c < CCH; ++c) {
    reinterpret_cast<float4*>(Cin)[(size_t)c * 2048 + gid] = carry;
    float4 a = reinterpret_cast<const float4*>(Ap)[(size_t)c * 2048 + gid];
    float4 hh = reinterpret_cast<const float4*>(Hp)[(size_t)c * 2048 + gid];
    carry.x = fmaf(a.x, carry.x, hh.x);
    carry.y = fmaf(a.y, carry.y, hh.y);
    carry.z = fmaf(a.z, carry.z, hh.z);
    carry.w = fmaf(a.w, carry.w, hh.w);
  }
}

// ---------- scan phase 3: replay with carry, write fp32 out ----------
__global__ __launch_bounds__(256) void k_scan3(const unsigned short* __restrict__ Gp,
                                               const unsigned short* __restrict__ Zp,
                                               const float* __restrict__ Cin,
                                               float* __restrict__ out) {
  const int gid = blockIdx.x * 256 + threadIdx.x;
  const int c = blockIdx.y;
  const int b = gid >> 8;
  const int d0 = (gid & 255) << 2;
  size_t base = ((size_t)b * S_ + (size_t)c * LCH) * 1024 + d0;
  float4 h = reinterpret_cast<const float4*>(Cin)[(size_t)c * 2048 + gid];
#pragma unroll 8
  for (int s = 0; s < LCH; ++s) {
    ushort4 zu = *reinterpret_cast<const ushort4*>(Zp + base);
    ushort4 gu = *reinterpret_cast<const ushort4*>(Gp + base);
    float z0 = bf2f(zu.x), z1 = bf2f(zu.y), z2 = bf2f(zu.z), z3 = bf2f(zu.w);
    h.x = fmaf(1.f - z0, h.x, z0 * bf2f(gu.x));
    h.y = fmaf(1.f - z1, h.y, z1 * bf2f(gu.y));
    h.z = fmaf(1.f - z2, h.z, z2 * bf2f(gu.z));
    h.w = fmaf(1.f - z3, h.w, z3 * bf2f(gu.w));
    *reinterpret_cast<float4*>(out + base) = h;
    base += 1024;
  }
}

extern "C" void kernel_launch(void* const* d_in, const int* in_sizes, int n_in,
                              void* d_out, int out_size, void* d_ws, size_t ws_size,
                              hipStream_t stream) {
  const float* x = (const float*)d_in[0];   // [8,4096,1024] f32
  const float* W = (const float*)d_in[1];   // [2048,1024]  f32
  float* out = (float*)d_out;               // [8,4096,1024] f32

  unsigned char* w = (unsigned char*)d_ws;
  // layout: xb(64MB) | wb(4MB) | Gp(64MB) | Zp(64MB). Ap/Hp/Cin alias xb
  // (xb is dead after k_gemm; 3 x 4MB << 64MB).
  unsigned short* xb = (unsigned short*)(w);
  unsigned short* wb = (unsigned short*)(w + 67108864);
  unsigned short* Gp = (unsigned short*)(w + 67108864 + 4194304);
  unsigned short* Zp = (unsigned short*)(w + 67108864 + 4194304 + 67108864);
  float* Ap  = (float*)(w);
  float* Hp  = (float*)(w + 4194304);
  float* Cin = (float*)(w + 8388608);

  k_cvt<<<4096, 256, 0, stream>>>(x, xb, (M_ * K_) / 4);
  k_cvt<<<2048, 256, 0, stream>>>(W, wb, (N_ * K_) / 4);
  k_gemm<<<(M_ / 256) * (N_ / 256), 512, 0, stream>>>(xb, wb, Gp, Zp);
  k_scan1<<<dim3(8, CCH), 256, 0, stream>>>(Gp, Zp, Ap, Hp);
  k_scan2<<<8, 256, 0, stream>>>(Ap, Hp, Cin);
  k_scan3<<<dim3(8, CCH), 256, 0, stream>>>(Gp, Zp, Cin, out);
}